// Round 1
// baseline (2225.298 us; speedup 1.0000x reference)
//
#include <hip/hip_runtime.h>

#define B_ 8
#define NN 4096
#define C_ 256
#define CK_ 32

// ---------------- Kernel 1: projections f = xWf+bf, g = xWg+bg, h = xWh+bh ---
// 16 rows per block, 320 threads: t<32 -> f col, t<64 -> g col, else h col.
__global__ __launch_bounds__(320) void proj_kernel(
    const float* __restrict__ x,
    const float* __restrict__ Wf, const float* __restrict__ bf,
    const float* __restrict__ Wg, const float* __restrict__ bg,
    const float* __restrict__ Wh, const float* __restrict__ bh,
    float* __restrict__ f, float* __restrict__ g, float* __restrict__ h)
{
    __shared__ __align__(16) float xs[16][256];
    const int t = threadIdx.x;
    const int row0 = blockIdx.x * 16;

    for (int idx = t; idx < 16 * 256; idx += 320) {
        xs[idx >> 8][idx & 255] = x[row0 * 256 + idx];  // x is row-major [rows][256]
    }
    __syncthreads();

    const float* Wcol;
    float bias;
    float* outp;
    int ld, wld;
    if (t < 32) {
        Wcol = Wf + t; bias = bf[t]; outp = f + row0 * CK_ + t; ld = CK_; wld = CK_;
    } else if (t < 64) {
        int c = t - 32;
        Wcol = Wg + c; bias = bg[c]; outp = g + row0 * CK_ + c; ld = CK_; wld = CK_;
    } else {
        int c = t - 64;
        Wcol = Wh + c; bias = bh[c]; outp = h + row0 * C_ + c; ld = C_; wld = C_;
    }

    float acc[16];
#pragma unroll
    for (int r = 0; r < 16; r++) acc[r] = 0.f;

    for (int k4 = 0; k4 < 64; k4++) {
        float w0 = Wcol[(k4 * 4 + 0) * wld];
        float w1 = Wcol[(k4 * 4 + 1) * wld];
        float w2 = Wcol[(k4 * 4 + 2) * wld];
        float w3 = Wcol[(k4 * 4 + 3) * wld];
#pragma unroll
        for (int r = 0; r < 16; r++) {
            float4 xv = *(const float4*)&xs[r][k4 * 4];
            acc[r] = fmaf(xv.w, w3, fmaf(xv.z, w2, fmaf(xv.y, w1, fmaf(xv.x, w0, acc[r]))));
        }
    }
#pragma unroll
    for (int r = 0; r < 16; r++) outp[r * ld] = acc[r] + bias;
}

// ---------------- Kernel 2: flash attention + residual -----------------------
// Block = 256 thr (4 waves), one (batch, 64-query tile) per block, 512 blocks.
// Wave w owns query rows w*16..w*16+15; lanes <-> 64 keys of current key tile.
__global__ __launch_bounds__(256, 2) void attn_kernel(
    const float* __restrict__ fm, const float* __restrict__ gm,
    const float* __restrict__ hm, const float* __restrict__ x,
    const float* __restrict__ gamma_p, float* __restrict__ out)
{
    __shared__ __align__(16) float gs[64][36];      // padded: conflict-free b128
    __shared__ __align__(16) float fs[64][36];
    __shared__ __align__(16) float pt[4][64][20];   // per-wave p, [key][query]

    const int tid = threadIdx.x;
    const int lane = tid & 63;
    const int wv = tid >> 6;
    const int b = blockIdx.x >> 6;
    const int qt = blockIdx.x & 63;
    const int base = b * NN;
    const int q0 = qt * 64;

    for (int idx = tid; idx < 64 * CK_; idx += 256) {
        int r = idx >> 5, k = idx & 31;
        gs[r][k] = gm[(base + q0 + r) * CK_ + k];
    }
    __syncthreads();

    float m[16], l[16], acc[16][4];
#pragma unroll
    for (int q = 0; q < 16; q++) {
        m[q] = -1e30f; l[q] = 0.f;
        acc[q][0] = acc[q][1] = acc[q][2] = acc[q][3] = 0.f;
    }

    for (int kt = 0; kt < NN / 64; kt++) {
        __syncthreads();  // protect fs overwrite vs previous iteration's readers
        for (int idx = tid; idx < 64 * CK_; idx += 256) {
            int r = idx >> 5, k = idx & 31;
            fs[r][k] = fm[(base + kt * 64 + r) * CK_ + k];
        }
        __syncthreads();

        // f row for this lane's key -> registers (reused across 16 queries)
        float4 f4[8];
#pragma unroll
        for (int k4 = 0; k4 < 8; k4++) f4[k4] = *(const float4*)&fs[lane][k4 * 4];

        // s[q] = <g_q, f_lane>
        float p[16];
#pragma unroll
        for (int q = 0; q < 16; q++) {
            const float* gr = gs[wv * 16 + q];
            float s0 = 0.f, s1 = 0.f, s2 = 0.f, s3 = 0.f;
#pragma unroll
            for (int k4 = 0; k4 < 8; k4++) {
                float4 g4 = *(const float4*)(gr + k4 * 4);
                s0 = fmaf(g4.x, f4[k4].x, s0);
                s1 = fmaf(g4.y, f4[k4].y, s1);
                s2 = fmaf(g4.z, f4[k4].z, s2);
                s3 = fmaf(g4.w, f4[k4].w, s3);
            }
            p[q] = (s0 + s1) + (s2 + s3);
        }

        // online softmax (per query row, reduce across 64 lanes = keys)
#pragma unroll
        for (int q = 0; q < 16; q++) {
            float tmax = p[q];
#pragma unroll
            for (int off = 32; off > 0; off >>= 1) tmax = fmaxf(tmax, __shfl_xor(tmax, off));
            float mnew = fmaxf(m[q], tmax);
            float pe = __expf(p[q] - mnew);
            float sum = pe;
#pragma unroll
            for (int off = 32; off > 0; off >>= 1) sum += __shfl_xor(sum, off);
            float scale = __expf(m[q] - mnew);
            l[q] = l[q] * scale + sum;
            m[q] = mnew;
            acc[q][0] *= scale; acc[q][1] *= scale;
            acc[q][2] *= scale; acc[q][3] *= scale;
            p[q] = pe;
        }

        // transpose p into wave-private LDS: pt[wv][key=lane][query]
#pragma unroll
        for (int q4 = 0; q4 < 4; q4++) {
            float4 v = make_float4(p[q4 * 4 + 0], p[q4 * 4 + 1], p[q4 * 4 + 2], p[q4 * 4 + 3]);
            *(float4*)&pt[wv][lane][q4 * 4] = v;
        }
        // same-wave LDS RAW: in-order per wave, no block barrier needed

        // PV: acc[q][0..3] += p[q][j] * h[j][lane*4 .. lane*4+3]
        const float* hb = hm + (base + kt * 64) * C_ + (lane << 2);
#pragma unroll 4
        for (int j = 0; j < 64; j++) {
            float4 h4 = *(const float4*)(hb + j * C_);
            const float* pr = pt[wv][j];
#pragma unroll
            for (int q4 = 0; q4 < 4; q4++) {
                float4 p4 = *(const float4*)(pr + q4 * 4);
                acc[q4 * 4 + 0][0] = fmaf(p4.x, h4.x, acc[q4 * 4 + 0][0]);
                acc[q4 * 4 + 0][1] = fmaf(p4.x, h4.y, acc[q4 * 4 + 0][1]);
                acc[q4 * 4 + 0][2] = fmaf(p4.x, h4.z, acc[q4 * 4 + 0][2]);
                acc[q4 * 4 + 0][3] = fmaf(p4.x, h4.w, acc[q4 * 4 + 0][3]);
                acc[q4 * 4 + 1][0] = fmaf(p4.y, h4.x, acc[q4 * 4 + 1][0]);
                acc[q4 * 4 + 1][1] = fmaf(p4.y, h4.y, acc[q4 * 4 + 1][1]);
                acc[q4 * 4 + 1][2] = fmaf(p4.y, h4.z, acc[q4 * 4 + 1][2]);
                acc[q4 * 4 + 1][3] = fmaf(p4.y, h4.w, acc[q4 * 4 + 1][3]);
                acc[q4 * 4 + 2][0] = fmaf(p4.z, h4.x, acc[q4 * 4 + 2][0]);
                acc[q4 * 4 + 2][1] = fmaf(p4.z, h4.y, acc[q4 * 4 + 2][1]);
                acc[q4 * 4 + 2][2] = fmaf(p4.z, h4.z, acc[q4 * 4 + 2][2]);
                acc[q4 * 4 + 2][3] = fmaf(p4.z, h4.w, acc[q4 * 4 + 2][3]);
                acc[q4 * 4 + 3][0] = fmaf(p4.w, h4.x, acc[q4 * 4 + 3][0]);
                acc[q4 * 4 + 3][1] = fmaf(p4.w, h4.y, acc[q4 * 4 + 3][1]);
                acc[q4 * 4 + 3][2] = fmaf(p4.w, h4.z, acc[q4 * 4 + 3][2]);
                acc[q4 * 4 + 3][3] = fmaf(p4.w, h4.w, acc[q4 * 4 + 3][3]);
            }
        }
    }

    // epilogue: out = gamma * (acc / l) + x
    const float gamma = *gamma_p;
    const int qw = q0 + wv * 16;
#pragma unroll
    for (int q = 0; q < 16; q++) {
        float inv = 1.f / l[q];
        int o = (base + qw + q) * C_ + (lane << 2);
        float4 xv = *(const float4*)(x + o);
        float4 r;
        r.x = fmaf(gamma, acc[q][0] * inv, xv.x);
        r.y = fmaf(gamma, acc[q][1] * inv, xv.y);
        r.z = fmaf(gamma, acc[q][2] * inv, xv.z);
        r.w = fmaf(gamma, acc[q][3] * inv, xv.w);
        *(float4*)(out + o) = r;
    }
}

extern "C" void kernel_launch(void* const* d_in, const int* in_sizes, int n_in,
                              void* d_out, int out_size, void* d_ws, size_t ws_size,
                              hipStream_t stream) {
    const float* x     = (const float*)d_in[0];
    const float* Wf    = (const float*)d_in[1];
    const float* bf    = (const float*)d_in[2];
    const float* Wg    = (const float*)d_in[3];
    const float* bg    = (const float*)d_in[4];
    const float* Wh    = (const float*)d_in[5];
    const float* bh    = (const float*)d_in[6];
    const float* gamma = (const float*)d_in[7];
    float* out = (float*)d_out;

    float* f = (float*)d_ws;                       // [B*N][32]  4 MB
    float* g = f + (size_t)B_ * NN * CK_;          // [B*N][32]  4 MB
    float* h = g + (size_t)B_ * NN * CK_;          // [B*N][256] 33.5 MB

    proj_kernel<<<(B_ * NN) / 16, 320, 0, stream>>>(x, Wf, bf, Wg, bg, Wh, bh, f, g, h);
    attn_kernel<<<B_ * (NN / 64), 256, 0, stream>>>(f, g, h, x, gamma, out);
}

// Round 4
// 410.405 us; speedup vs baseline: 5.4222x; 5.4222x over previous
//
#include <hip/hip_runtime.h>

#define B_ 8
#define NN 4096
#define C_ 256
#define CK_ 32

typedef __attribute__((ext_vector_type(8))) short bf16x8;
typedef __attribute__((ext_vector_type(4))) float f32x4;
typedef __attribute__((ext_vector_type(4))) unsigned int u32x4;

typedef const __attribute__((address_space(1))) void* gas_ptr;
typedef __attribute__((address_space(3))) void* las_ptr;

__device__ __forceinline__ void gload16(const void* src, void* dst) {
    __builtin_amdgcn_global_load_lds((gas_ptr)src, (las_ptr)dst, 16, 0, 0);
}

__device__ __forceinline__ ushort bf16_rne(float v) {
    unsigned u = __builtin_bit_cast(unsigned, v);
    unsigned r = (u + 0x7fffu + ((u >> 16) & 1u)) >> 16;
    return (ushort)r;
}
__device__ __forceinline__ float bf16_to_f(ushort h) {
    return __builtin_bit_cast(float, (unsigned)h << 16);
}

// ---------------- Kernel 1: projections -> bf16 hi/lo f,g ; bf16 h^T ---------
// 16 rows/block, 320 thr: t<32 f-col, t<64 g-col, else h-col (256).
__global__ __launch_bounds__(320) void proj_kernel(
    const float* __restrict__ x,
    const float* __restrict__ Wf, const float* __restrict__ bf,
    const float* __restrict__ Wg, const float* __restrict__ bg,
    const float* __restrict__ Wh, const float* __restrict__ bh,
    ushort* __restrict__ fh, ushort* __restrict__ fl,
    ushort* __restrict__ gh, ushort* __restrict__ gl,
    ushort* __restrict__ ht)
{
    __shared__ __align__(16) float xs[16][256];
    const int t = threadIdx.x;
    const int row0 = blockIdx.x * 16;
    const int bb = row0 >> 12;       // batch
    const int n0 = row0 & 4095;      // row within batch

    for (int idx = t; idx < 16 * 256; idx += 320)
        xs[idx >> 8][idx & 255] = x[row0 * 256 + idx];
    __syncthreads();

    const float* Wcol; float bias; int wld;
    if (t < 32)      { Wcol = Wf + t;        bias = bf[t];      wld = CK_; }
    else if (t < 64) { Wcol = Wg + (t - 32); bias = bg[t - 32]; wld = CK_; }
    else             { Wcol = Wh + (t - 64); bias = bh[t - 64]; wld = C_;  }

    float acc[16];
#pragma unroll
    for (int r = 0; r < 16; r++) acc[r] = 0.f;

    for (int k4 = 0; k4 < 64; k4++) {
        float w0 = Wcol[(k4 * 4 + 0) * wld];
        float w1 = Wcol[(k4 * 4 + 1) * wld];
        float w2 = Wcol[(k4 * 4 + 2) * wld];
        float w3 = Wcol[(k4 * 4 + 3) * wld];
#pragma unroll
        for (int r = 0; r < 16; r++) {
            float4 xv = *(const float4*)&xs[r][k4 * 4];
            acc[r] = fmaf(xv.w, w3, fmaf(xv.z, w2, fmaf(xv.y, w1, fmaf(xv.x, w0, acc[r]))));
        }
    }
    __syncthreads();  // xs reads done; reuse as bf16 staging

    ushort* st_hi = (ushort*)&xs[0][0];         // [16][64]
    ushort* st_lo = st_hi + 16 * 64;            // [16][64]

    if (t < 64) {
#pragma unroll
        for (int r = 0; r < 16; r++) {
            float v = acc[r] + bias;
            ushort hi = bf16_rne(v);
            ushort lo = bf16_rne(v - bf16_to_f(hi));
            st_hi[r * 64 + t] = hi;
            st_lo[r * 64 + t] = lo;
        }
    } else {
        const int c = t - 64;
        unsigned w[8];
#pragma unroll
        for (int i = 0; i < 8; i++) {
            ushort h0 = bf16_rne(acc[2 * i] + bias);
            ushort h1 = bf16_rne(acc[2 * i + 1] + bias);
            w[i] = (unsigned)h0 | ((unsigned)h1 << 16);
        }
        u32x4* dst = (u32x4*)(ht + (size_t)(bb * 256 + c) * 4096 + n0);
        dst[0] = (u32x4){w[0], w[1], w[2], w[3]};
        dst[1] = (u32x4){w[4], w[5], w[6], w[7]};
    }
    __syncthreads();

    if (t < 256) {
        const int r = t >> 4, dc = t & 15;
        unsigned vfh = st_hi[r * 64 + dc * 2] | ((unsigned)st_hi[r * 64 + dc * 2 + 1] << 16);
        unsigned vfl = st_lo[r * 64 + dc * 2] | ((unsigned)st_lo[r * 64 + dc * 2 + 1] << 16);
        unsigned vgh = st_hi[r * 64 + 32 + dc * 2] | ((unsigned)st_hi[r * 64 + 32 + dc * 2 + 1] << 16);
        unsigned vgl = st_lo[r * 64 + 32 + dc * 2] | ((unsigned)st_lo[r * 64 + 32 + dc * 2 + 1] << 16);
        const int o = (row0 + r) * 16 + dc;
        ((unsigned*)fh)[o] = vfh;
        ((unsigned*)fl)[o] = vfl;
        ((unsigned*)gh)[o] = vgh;
        ((unsigned*)gl)[o] = vgl;
    }
}

// ---------------- Kernel 2: MFMA flash attention + residual ------------------
// 512 blocks = (batch, 64-q tile); 4 waves x 16 q-rows; 64-key tiles.
__global__ __launch_bounds__(256, 2) void attn_kernel(
    const ushort* __restrict__ fh, const ushort* __restrict__ fl,
    const ushort* __restrict__ gh, const ushort* __restrict__ gl,
    const ushort* __restrict__ ht, const float* __restrict__ x,
    const float* __restrict__ gammap, float* __restrict__ out)
{
    __shared__ __align__(16) ushort Fh[2048];    // 4 frags x 64 lanes x 8
    __shared__ __align__(16) ushort Fl[2048];
    __shared__ __align__(16) ushort Hts[16384];  // 32 frags (kh,ct)
    __shared__ __align__(16) float  ptb[4][64 * 21];  // per-wave P^T, stride 21

    const int tid = threadIdx.x;
    const int l = tid & 63, wv = tid >> 6;
    const int grp = l >> 4, a = l & 15;
    const int b = blockIdx.x >> 6;
    const int q0 = (blockIdx.x & 63) * 64;
    const int base = b * NN;

    // wave's A-fragments of G (hi/lo): lane holds G[q0+wv*16+a][8*grp .. +7]
    const size_t grow = (size_t)(base + q0 + wv * 16 + a) * CK_ + grp * 8;
    bf16x8 agh = *(const bf16x8*)(gh + grow);
    bf16x8 agl = *(const bf16x8*)(gl + grow);

    float m[4], lsum[4];
    f32x4 acc[16];
#pragma unroll
    for (int r = 0; r < 4; r++) { m[r] = -1e30f; lsum[r] = 0.f; }
#pragma unroll
    for (int ct = 0; ct < 16; ct++) acc[ct] = (f32x4){0.f, 0.f, 0.f, 0.f};

    float* ptw = &ptb[wv][0];

    for (int kt = 0; kt < NN / 64; kt++) {
        __syncthreads();  // previous tile's LDS readers done

        // stage F (frag wv) and 8 Ht frags, per wave, via global_load_lds
        {
            const size_t frow = (size_t)(base + kt * 64 + wv * 16 + a) * CK_ + grp * 8;
            gload16(fh + frow, &Fh[wv * 512]);
            gload16(fl + frow, &Fl[wv * 512]);
#pragma unroll
            for (int i = 0; i < 8; i++) {
                const int fr = wv * 8 + i;
                const int khh = fr >> 4, ct = fr & 15;
                const ushort* hsrc = ht + (size_t)(b * 256 + ct * 16 + a) * 4096
                                        + (size_t)(kt * 64 + khh * 32 + grp * 8);
                gload16(hsrc, &Hts[fr * 512]);
            }
        }
        __syncthreads();  // staging drained (vmcnt(0) before barrier)

        // ---- QK^T: S[16q x 64key], split-precision (3 MFMAs per 16-key tile)
        f32x4 s4[4];
#pragma unroll
        for (int s = 0; s < 4; s++) {
            bf16x8 bhk = *(const bf16x8*)&Fh[(s * 64 + l) * 8];
            bf16x8 blk = *(const bf16x8*)&Fl[(s * 64 + l) * 8];
            f32x4 z = (f32x4){0.f, 0.f, 0.f, 0.f};
            z = __builtin_amdgcn_mfma_f32_16x16x32_bf16(agh, bhk, z, 0, 0, 0);
            z = __builtin_amdgcn_mfma_f32_16x16x32_bf16(agh, blk, z, 0, 0, 0);
            z = __builtin_amdgcn_mfma_f32_16x16x32_bf16(agl, bhk, z, 0, 0, 0);
            s4[s] = z;
        }

        // ---- online softmax; lane holds S[q=grp*4+r][key=s*16+a]
        float pmax[4];
#pragma unroll
        for (int r = 0; r < 4; r++) {
            float v = fmaxf(fmaxf(s4[0][r], s4[1][r]), fmaxf(s4[2][r], s4[3][r]));
#pragma unroll
            for (int off = 8; off > 0; off >>= 1) v = fmaxf(v, __shfl_xor(v, off));
            pmax[r] = v;
        }
        int defer = (pmax[0] <= m[0] + 8.f) && (pmax[1] <= m[1] + 8.f) &&
                    (pmax[2] <= m[2] + 8.f) && (pmax[3] <= m[3] + 8.f);
        if (!__all(defer)) {
            float sc[4];
#pragma unroll
            for (int r = 0; r < 4; r++) {
                float mn = fmaxf(m[r], pmax[r]);
                sc[r] = __expf(m[r] - mn);
                m[r] = mn;
                lsum[r] *= sc[r];
            }
#pragma unroll
            for (int ct = 0; ct < 16; ct++) {
#pragma unroll
                for (int r = 0; r < 4; r++) acc[ct][r] *= sc[r];
            }
        }

        float p[4][4], rs[4] = {0.f, 0.f, 0.f, 0.f};
#pragma unroll
        for (int s = 0; s < 4; s++) {
#pragma unroll
            for (int r = 0; r < 4; r++) {
                float pe = __expf(s4[s][r] - m[r]);
                p[s][r] = pe;
                rs[r] += pe;
            }
        }
#pragma unroll
        for (int r = 0; r < 4; r++) {
            float v = rs[r];
#pragma unroll
            for (int off = 8; off > 0; off >>= 1) v += __shfl_xor(v, off);
            lsum[r] += v;
        }

        // ---- P^T -> wave-private LDS (stride 21: conflict-free both ways)
#pragma unroll
        for (int s = 0; s < 4; s++) {
#pragma unroll
            for (int r = 0; r < 4; r++)
                ptw[(s * 16 + a) * 21 + grp * 4 + r] = p[s][r];
        }
        // same-wave LDS RAW: program order within wave, no barrier

        // ---- PV: acc[ct] += P(16q x 32k) * H(32k x 16c) for kh = 0,1
#pragma unroll
        for (int kh = 0; kh < 2; kh++) {
            bf16x8 pa;
#pragma unroll
            for (int e = 0; e < 8; e++) {
                float v = ptw[(kh * 32 + grp * 8 + e) * 21 + a];
                pa[e] = (short)bf16_rne(v);
            }
#pragma unroll
            for (int ct = 0; ct < 16; ct++) {
                bf16x8 hb = *(const bf16x8*)&Hts[((kh * 16 + ct) * 64 + l) * 8];
                acc[ct] = __builtin_amdgcn_mfma_f32_16x16x32_bf16(pa, hb, acc[ct], 0, 0, 0);
            }
        }
    }

    // ---- epilogue: out = gamma * acc/l + x
    const float gamma = *gammap;
    float inv[4];
#pragma unroll
    for (int r = 0; r < 4; r++) inv[r] = 1.f / lsum[r];
#pragma unroll
    for (int ct = 0; ct < 16; ct++) {
#pragma unroll
        for (int r = 0; r < 4; r++) {
            const int row = base + q0 + wv * 16 + grp * 4 + r;
            const int o = row * C_ + ct * 16 + a;
            out[o] = fmaf(gamma, acc[ct][r] * inv[r], x[o]);
        }
    }
}

extern "C" void kernel_launch(void* const* d_in, const int* in_sizes, int n_in,
                              void* d_out, int out_size, void* d_ws, size_t ws_size,
                              hipStream_t stream) {
    const float* x     = (const float*)d_in[0];
    const float* Wf    = (const float*)d_in[1];
    const float* bfp   = (const float*)d_in[2];
    const float* Wg    = (const float*)d_in[3];
    const float* bgp   = (const float*)d_in[4];
    const float* Wh    = (const float*)d_in[5];
    const float* bhp   = (const float*)d_in[6];
    const float* gamma = (const float*)d_in[7];
    float* out = (float*)d_out;

    const size_t npix = (size_t)B_ * NN;
    ushort* fh = (ushort*)d_ws;            // [B*N][32] bf16 hi
    ushort* fl = fh + npix * CK_;
    ushort* gh = fl + npix * CK_;
    ushort* gl = gh + npix * CK_;
    ushort* ht = gl + npix * CK_;          // [B][256][4096] bf16 (h transposed)

    proj_kernel<<<(B_ * NN) / 16, 320, 0, stream>>>(x, Wf, bfp, Wg, bgp, Wh, bhp,
                                                    fh, fl, gh, gl, ht);
    attn_kernel<<<B_ * (NN / 64), 256, 0, stream>>>(fh, fl, gh, gl, ht, x, gamma, out);
}

// Round 5
// 404.625 us; speedup vs baseline: 5.4997x; 1.0143x over previous
//
#include <hip/hip_runtime.h>

#define B_ 8
#define NN 4096
#define C_ 256
#define CK_ 32

typedef __attribute__((ext_vector_type(8))) short bf16x8;
typedef __attribute__((ext_vector_type(4))) float f32x4;
typedef __attribute__((ext_vector_type(4))) unsigned int u32x4;

typedef const __attribute__((address_space(1))) void* gas_ptr;
typedef __attribute__((address_space(3))) void* las_ptr;

__device__ __forceinline__ void gload16(const void* src, void* dst) {
    __builtin_amdgcn_global_load_lds((gas_ptr)src, (las_ptr)dst, 16, 0, 0);
}
__device__ __forceinline__ ushort bf16_rne(float v) {
    unsigned u = __builtin_bit_cast(unsigned, v);
    unsigned r = (u + 0x7fffu + ((u >> 16) & 1u)) >> 16;
    return (ushort)r;
}
__device__ __forceinline__ float bf16_to_f(ushort h) {
    return __builtin_bit_cast(float, (unsigned)h << 16);
}
#define MFMA16 __builtin_amdgcn_mfma_f32_16x16x32_bf16

// ---------------- Kernel 0: pack W -> bf16 hi/lo MFMA fragments --------------
// idx = ((ct*8 + kc)*64 + lane)*8 + e ; frag element = W[k = kc*32+(lane>>4)*8+e][col(ct, lane&15)]
__global__ __launch_bounds__(256) void prep_kernel(
    const float* __restrict__ Wf, const float* __restrict__ Wg,
    const float* __restrict__ Wh,
    ushort* __restrict__ whi, ushort* __restrict__ wlo)
{
    const int idx = blockIdx.x * 256 + threadIdx.x;   // grid = 320 blocks -> 81920
    const int e = idx & 7, ll = (idx >> 3) & 63, kc = (idx >> 9) & 7, ct = idx >> 12;
    const int k = kc * 32 + (ll >> 4) * 8 + e;
    const int a = ll & 15;
    float v;
    if (ct < 2)      v = Wf[k * 32 + ct * 16 + a];
    else if (ct < 4) v = Wg[k * 32 + (ct - 2) * 16 + a];
    else             v = Wh[k * 256 + (ct - 4) * 16 + a];
    const ushort hi = bf16_rne(v);
    whi[idx] = hi;
    wlo[idx] = bf16_rne(v - bf16_to_f(hi));
}

// ---------------- Kernel 1: MFMA projections ---------------------------------
// 512 blocks x 64 rows; 4 waves, wave = 16 rows x 320 cols (20 col-tiles).
// 3-term hi/lo split: xh*wh + xl*wh + xh*wl (fp32-accurate to ~1e-5).
__global__ __launch_bounds__(256, 2) void proj_kernel(
    const float* __restrict__ x,
    const ushort* __restrict__ whi, const ushort* __restrict__ wlo,
    const float* __restrict__ bfp, const float* __restrict__ bgp,
    const float* __restrict__ bhp,
    ushort* __restrict__ fh, ushort* __restrict__ fl,
    ushort* __restrict__ gh, ushort* __restrict__ gl,
    ushort* __restrict__ ht)
{
    __shared__ __align__(16) float xs[64 * 256];   // 64 KB, XOR-swizzled content
    const int tid = threadIdx.x, l = tid & 63, wv = tid >> 6;
    const int g = l >> 4, a = l & 15;
    const int rowbase = blockIdx.x * 64;
    const int bb = rowbase >> 12, n0 = rowbase & 4095;

    // stage x: LDS linear dest, source pre-swizzled (rule #21):
    // LDS[row][B] holds x[row][B ^ ((row&7)<<4)]  (byte offsets, 16B granular)
#pragma unroll
    for (int i = 0; i < 16; i++) {
        const int row = wv * 16 + i;
        const float* src = x + (size_t)(rowbase + row) * 256
                         + ((unsigned)((l * 16) ^ ((i & 7) << 4)) >> 2);
        gload16(src, &xs[row * 256]);
    }
    __syncthreads();

    // x fragments (lane holds X[row = wv*16+a][k = kc*32 + g*8 .. +7]) hi/lo
    bf16x8 xh[8], xl[8];
    {
        const int swz = (a & 7) << 4;
        const char* rbase = (const char*)&xs[(wv * 16 + a) * 256];
#pragma unroll
        for (int kc = 0; kc < 8; kc++) {
            f32x4 v0 = *(const f32x4*)(rbase + (((kc * 128 + g * 32) + 0) ^ swz));
            f32x4 v1 = *(const f32x4*)(rbase + (((kc * 128 + g * 32) + 16) ^ swz));
#pragma unroll
            for (int e = 0; e < 4; e++) {
                ushort hi = bf16_rne(v0[e]);
                xh[kc][e] = (short)hi;
                xl[kc][e] = (short)bf16_rne(v0[e] - bf16_to_f(hi));
            }
#pragma unroll
            for (int e = 0; e < 4; e++) {
                ushort hi = bf16_rne(v1[e]);
                xh[kc][4 + e] = (short)hi;
                xl[kc][4 + e] = (short)bf16_rne(v1[e] - bf16_to_f(hi));
            }
        }
    }

#pragma unroll
    for (int ct = 0; ct < 20; ct++) {
        f32x4 acc = (f32x4){0.f, 0.f, 0.f, 0.f};
#pragma unroll
        for (int kc = 0; kc < 8; kc++) {
            const size_t fo = (size_t)((ct * 8 + kc) * 64 + l) * 8;
            bf16x8 wh = *(const bf16x8*)(whi + fo);
            bf16x8 wl = *(const bf16x8*)(wlo + fo);
            if (ct < 4) {   // D[wcol][xrow]: lane = 4 wcols (g*4+r) x 1 xrow (a)
                acc = MFMA16(wh, xh[kc], acc, 0, 0, 0);
                acc = MFMA16(wh, xl[kc], acc, 0, 0, 0);
                acc = MFMA16(wl, xh[kc], acc, 0, 0, 0);
            } else {        // D[xrow][wcol]: lane = 4 xrows (g*4+r) x 1 wcol (a)
                acc = MFMA16(xh[kc], wh, acc, 0, 0, 0);
                acc = MFMA16(xl[kc], wh, acc, 0, 0, 0);
                acc = MFMA16(xh[kc], wl, acc, 0, 0, 0);
            }
        }
        if (ct < 4) {
            const float* bias = (ct < 2) ? bfp : bgp;
            const int colbase = (ct & 1) * 16 + g * 4;
            float4 bv = *(const float4*)&bias[colbase];
            float v0 = acc[0] + bv.x, v1 = acc[1] + bv.y;
            float v2 = acc[2] + bv.z, v3 = acc[3] + bv.w;
            ushort h0 = bf16_rne(v0), h1 = bf16_rne(v1), h2 = bf16_rne(v2), h3 = bf16_rne(v3);
            ushort l0 = bf16_rne(v0 - bf16_to_f(h0)), l1 = bf16_rne(v1 - bf16_to_f(h1));
            ushort l2 = bf16_rne(v2 - bf16_to_f(h2)), l3 = bf16_rne(v3 - bf16_to_f(h3));
            uint2 hw, lw;
            hw.x = (unsigned)h0 | ((unsigned)h1 << 16); hw.y = (unsigned)h2 | ((unsigned)h3 << 16);
            lw.x = (unsigned)l0 | ((unsigned)l1 << 16); lw.y = (unsigned)l2 | ((unsigned)l3 << 16);
            const size_t o = (size_t)(rowbase + wv * 16 + a) * 32 + colbase;
            if (ct < 2) { *(uint2*)&fh[o] = hw; *(uint2*)&fl[o] = lw; }
            else        { *(uint2*)&gh[o] = hw; *(uint2*)&gl[o] = lw; }
        } else {
            const int c = (ct - 4) * 16 + a;
            const float bias = bhp[c];
            ushort h0 = bf16_rne(acc[0] + bias), h1 = bf16_rne(acc[1] + bias);
            ushort h2 = bf16_rne(acc[2] + bias), h3 = bf16_rne(acc[3] + bias);
            uint2 w;
            w.x = (unsigned)h0 | ((unsigned)h1 << 16);
            w.y = (unsigned)h2 | ((unsigned)h3 << 16);
            const size_t o = (size_t)(bb * 256 + c) * 4096 + n0 + wv * 16 + g * 4;
            *(uint2*)&ht[o] = w;
        }
    }
}

// ---------------- Kernel 2: MFMA flash attention + residual ------------------
// Swapped QK^T: lane owns one q-row's scores -> in-register softmax,
// shuffle-built PV A-fragments (no P LDS). 40KB LDS -> 4 blocks/CU.
__global__ __launch_bounds__(256, 4) void attn_kernel(
    const ushort* __restrict__ fh, const ushort* __restrict__ fl,
    const ushort* __restrict__ gh, const ushort* __restrict__ gl,
    const ushort* __restrict__ ht, const float* __restrict__ x,
    const float* __restrict__ gammap, float* __restrict__ out)
{
    __shared__ __align__(16) ushort Fh[2048];    // 4 frags x 64 lanes x 8
    __shared__ __align__(16) ushort Fl[2048];
    __shared__ __align__(16) ushort Hts[16384];  // 32 frags (kh,ct)

    const int tid = threadIdx.x;
    const int l = tid & 63, wv = tid >> 6;
    const int g = l >> 4, a = l & 15;
    // bijective XCD swizzle (512 = 8*64): each XCD gets one batch's blocks
    const int bid = blockIdx.x;
    const int swzb = ((bid & 7) << 6) + (bid >> 3);
    const int b = swzb >> 6;
    const int q0 = (swzb & 63) * 64;
    const int base = b * NN;

    // G fragments: lane holds G[q0+wv*16+a][g*8 .. +7] (hi/lo)
    const size_t grow = (size_t)(base + q0 + wv * 16 + a) * CK_ + g * 8;
    const bf16x8 agh = *(const bf16x8*)(gh + grow);
    const bf16x8 agl = *(const bf16x8*)(gl + grow);

    float m = -1e30f, lsum = 0.f;   // per-lane softmax state for q = a
    f32x4 acc[16];
#pragma unroll
    for (int ct = 0; ct < 16; ct++) acc[ct] = (f32x4){0.f, 0.f, 0.f, 0.f};

    for (int kt = 0; kt < NN / 64; kt++) {
        __syncthreads();  // previous tile's LDS readers done
        {
            const size_t frow = (size_t)(base + kt * 64 + wv * 16 + a) * CK_ + g * 8;
            gload16(fh + frow, &Fh[wv * 512]);
            gload16(fl + frow, &Fl[wv * 512]);
#pragma unroll
            for (int i = 0; i < 8; i++) {
                const int fr = wv * 8 + i;
                const int khh = fr >> 4, ct = fr & 15;
                const ushort* hsrc = ht + (size_t)(b * 256 + ct * 16 + a) * 4096
                                        + (size_t)(kt * 64 + khh * 32 + g * 8);
                gload16(hsrc, &Hts[fr * 512]);
            }
        }
        __syncthreads();  // staging drained

        // ---- swapped QK^T: D[key][q]; lane: q = a, keys = s*16 + g*4 + r
        f32x4 s4[4];
#pragma unroll
        for (int s = 0; s < 4; s++) {
            bf16x8 bhk = *(const bf16x8*)&Fh[(s * 64 + l) * 8];
            bf16x8 blk = *(const bf16x8*)&Fl[(s * 64 + l) * 8];
            f32x4 z = (f32x4){0.f, 0.f, 0.f, 0.f};
            z = MFMA16(bhk, agh, z, 0, 0, 0);
            z = MFMA16(blk, agh, z, 0, 0, 0);
            z = MFMA16(bhk, agl, z, 0, 0, 0);
            s4[s] = z;
        }

        // ---- per-lane online softmax over this lane's 16 keys, reduce over g
        float pm = s4[0][0];
#pragma unroll
        for (int s = 0; s < 4; s++)
#pragma unroll
            for (int r = 0; r < 4; r++) pm = fmaxf(pm, s4[s][r]);
        pm = fmaxf(pm, __shfl_xor(pm, 16));
        pm = fmaxf(pm, __shfl_xor(pm, 32));

        const int defer = (pm <= m + 8.f);
        if (!__all(defer)) {
            const float mn = fmaxf(m, pm);
            const float scq = __expf(m - mn);
            m = mn; lsum *= scq;
            float scr[4];
#pragma unroll
            for (int r = 0; r < 4; r++) scr[r] = __shfl(scq, g * 4 + r);
#pragma unroll
            for (int ct = 0; ct < 16; ct++)
#pragma unroll
                for (int r = 0; r < 4; r++) acc[ct][r] *= scr[r];
        }

        float p[4][4], rsum = 0.f;
#pragma unroll
        for (int s = 0; s < 4; s++)
#pragma unroll
            for (int r = 0; r < 4; r++) {
                const float pe = __expf(s4[s][r] - m);
                p[s][r] = pe;
                rsum += pe;
            }
        rsum += __shfl_xor(rsum, 16);
        rsum += __shfl_xor(rsum, 32);
        lsum += rsum;

        // pack P to bf16 pairs: cw[s][j] = (p[s][2j], p[s][2j+1])
        unsigned cw[4][2];
#pragma unroll
        for (int s = 0; s < 4; s++) {
            cw[s][0] = (unsigned)bf16_rne(p[s][0]) | ((unsigned)bf16_rne(p[s][1]) << 16);
            cw[s][1] = (unsigned)bf16_rne(p[s][2]) | ((unsigned)bf16_rne(p[s][3]) << 16);
        }

        // ---- PV: build pa via shuffles; pa.word[w] = cw[kh*2+(g>>1)][w&1]
        //      from lane (2*(g&1) + (w>>1))*16 + a
        const int src0 = ((g & 1) << 5) + a;
        const int src1 = src0 + 16;
#pragma unroll
        for (int kh = 0; kh < 2; kh++) {
            const unsigned A0 = (unsigned)__shfl((int)cw[kh * 2][0], src0);
            const unsigned A1 = (unsigned)__shfl((int)cw[kh * 2][1], src0);
            const unsigned A2 = (unsigned)__shfl((int)cw[kh * 2][0], src1);
            const unsigned A3 = (unsigned)__shfl((int)cw[kh * 2][1], src1);
            const unsigned B0 = (unsigned)__shfl((int)cw[kh * 2 + 1][0], src0);
            const unsigned B1 = (unsigned)__shfl((int)cw[kh * 2 + 1][1], src0);
            const unsigned B2 = (unsigned)__shfl((int)cw[kh * 2 + 1][0], src1);
            const unsigned B3 = (unsigned)__shfl((int)cw[kh * 2 + 1][1], src1);
            const int hi = g >> 1;
            u32x4 pw;
            pw[0] = hi ? B0 : A0; pw[1] = hi ? B1 : A1;
            pw[2] = hi ? B2 : A2; pw[3] = hi ? B3 : A3;
            const bf16x8 pa = __builtin_bit_cast(bf16x8, pw);
#pragma unroll
            for (int ct = 0; ct < 16; ct++) {
                bf16x8 hb = *(const bf16x8*)&Hts[((kh * 16 + ct) * 64 + l) * 8];
                acc[ct] = MFMA16(pa, hb, acc[ct], 0, 0, 0);
            }
        }
    }

    // ---- epilogue: out = gamma * acc/l + x ; acc rows q = g*4+r
    const float gamma = *gammap;
    const float inv = 1.f / lsum;
    float invr[4];
#pragma unroll
    for (int r = 0; r < 4; r++) invr[r] = __shfl(inv, g * 4 + r);
#pragma unroll
    for (int ct = 0; ct < 16; ct++) {
#pragma unroll
        for (int r = 0; r < 4; r++) {
            const int row = base + q0 + wv * 16 + g * 4 + r;
            const int o = row * C_ + ct * 16 + a;
            out[o] = fmaf(gamma, acc[ct][r] * invr[r], x[o]);
        }
    }
}

extern "C" void kernel_launch(void* const* d_in, const int* in_sizes, int n_in,
                              void* d_out, int out_size, void* d_ws, size_t ws_size,
                              hipStream_t stream) {
    const float* x     = (const float*)d_in[0];
    const float* Wf    = (const float*)d_in[1];
    const float* bfp   = (const float*)d_in[2];
    const float* Wg    = (const float*)d_in[3];
    const float* bgp   = (const float*)d_in[4];
    const float* Wh    = (const float*)d_in[5];
    const float* bhp   = (const float*)d_in[6];
    const float* gamma = (const float*)d_in[7];
    float* out = (float*)d_out;

    const size_t npix = (size_t)B_ * NN;
    ushort* fh  = (ushort*)d_ws;             // [B*N][32] bf16 hi
    ushort* fl  = fh + npix * CK_;
    ushort* gh  = fl + npix * CK_;
    ushort* gl  = gh + npix * CK_;
    ushort* ht  = gl + npix * CK_;           // [B][256][4096] bf16 (h^T)
    ushort* whi = ht + (size_t)B_ * C_ * NN; // 20*8*64*8 W fragments
    ushort* wlo = whi + 20 * 8 * 64 * 8;

    prep_kernel<<<320, 256, 0, stream>>>(Wf, Wg, Wh, whi, wlo);
    proj_kernel<<<(B_ * NN) / 64, 256, 0, stream>>>(x, whi, wlo, bfp, bgp, bhp,
                                                    fh, fl, gh, gl, ht);
    attn_kernel<<<B_ * (NN / 64), 256, 0, stream>>>(fh, fl, gh, gl, ht, x, gamma, out);
}

// Round 8
// 293.369 us; speedup vs baseline: 7.5853x; 1.3792x over previous
//
#include <hip/hip_runtime.h>

#define B_ 8
#define NN 4096
#define C_ 256
#define CK_ 32

typedef __attribute__((ext_vector_type(8))) short bf16x8;
typedef __attribute__((ext_vector_type(4))) float f32x4;
typedef __attribute__((ext_vector_type(4))) unsigned int u32x4;

typedef const __attribute__((address_space(1))) void* gas_ptr;
typedef __attribute__((address_space(3))) void* las_ptr;

__device__ __forceinline__ void gload16(const void* src, void* dst) {
    __builtin_amdgcn_global_load_lds((gas_ptr)src, (las_ptr)dst, 16, 0, 0);
}
__device__ __forceinline__ ushort bf16_rne(float v) {
    unsigned u = __builtin_bit_cast(unsigned, v);
    unsigned r = (u + 0x7fffu + ((u >> 16) & 1u)) >> 16;
    return (ushort)r;
}
__device__ __forceinline__ float bf16_to_f(ushort h) {
    return __builtin_bit_cast(float, (unsigned)h << 16);
}
#define MFMA16 __builtin_amdgcn_mfma_f32_16x16x32_bf16

// ---------------- Kernel 0: pack W -> bf16 hi/lo MFMA fragments --------------
__global__ __launch_bounds__(256) void prep_kernel(
    const float* __restrict__ Wf, const float* __restrict__ Wg,
    const float* __restrict__ Wh,
    ushort* __restrict__ whi, ushort* __restrict__ wlo)
{
    const int idx = blockIdx.x * 256 + threadIdx.x;   // grid = 320 blocks
    const int e = idx & 7, ll = (idx >> 3) & 63, kc = (idx >> 9) & 7, ct = idx >> 12;
    const int k = kc * 32 + (ll >> 4) * 8 + e;
    const int a = ll & 15;
    float v;
    if (ct < 2)      v = Wf[k * 32 + ct * 16 + a];
    else if (ct < 4) v = Wg[k * 32 + (ct - 2) * 16 + a];
    else             v = Wh[k * 256 + (ct - 4) * 16 + a];
    const ushort hi = bf16_rne(v);
    whi[idx] = hi;
    wlo[idx] = bf16_rne(v - bf16_to_f(hi));
}

// ---------------- Kernel 1: MFMA projections ---------------------------------
// 512 blocks x 64 rows; h^T staged through LDS transpose -> coalesced stores.
__global__ __launch_bounds__(256, 2) void proj_kernel(
    const float* __restrict__ x,
    const ushort* __restrict__ whi, const ushort* __restrict__ wlo,
    const float* __restrict__ bfp, const float* __restrict__ bgp,
    const float* __restrict__ bhp,
    ushort* __restrict__ fh, ushort* __restrict__ fl,
    ushort* __restrict__ gh, ushort* __restrict__ gl,
    ushort* __restrict__ ht)
{
    __shared__ __align__(16) float xs[64 * 256];   // 64 KB; later aliased as h^T
    ushort* hs = (ushort*)xs;                      // [256][80] padded h^T tile
    const int tid = threadIdx.x, l = tid & 63, wv = tid >> 6;
    const int g = l >> 4, a = l & 15;
    const int rowbase = blockIdx.x * 64;
    const int bb = rowbase >> 12, n0 = rowbase & 4095;

    // stage x: LDS linear dest, source pre-swizzled (both-sides rule)
#pragma unroll
    for (int i = 0; i < 16; i++) {
        const int row = wv * 16 + i;
        const float* src = x + (size_t)(rowbase + row) * 256
                         + ((unsigned)((l * 16) ^ ((i & 7) << 4)) >> 2);
        gload16(src, &xs[row * 256]);
    }
    __syncthreads();

    // x fragments (lane holds X[row = wv*16+a][k = kc*32 + g*8 .. +7]) hi/lo
    bf16x8 xh[8], xl[8];
    {
        const int swz = (a & 7) << 4;
        const char* rbase = (const char*)&xs[(wv * 16 + a) * 256];
#pragma unroll
        for (int kc = 0; kc < 8; kc++) {
            f32x4 v0 = *(const f32x4*)(rbase + (((kc * 128 + g * 32) + 0) ^ swz));
            f32x4 v1 = *(const f32x4*)(rbase + (((kc * 128 + g * 32) + 16) ^ swz));
#pragma unroll
            for (int e = 0; e < 4; e++) {
                ushort hi = bf16_rne(v0[e]);
                xh[kc][e] = (short)hi;
                xl[kc][e] = (short)bf16_rne(v0[e] - bf16_to_f(hi));
            }
#pragma unroll
            for (int e = 0; e < 4; e++) {
                ushort hi = bf16_rne(v1[e]);
                xh[kc][4 + e] = (short)hi;
                xl[kc][4 + e] = (short)bf16_rne(v1[e] - bf16_to_f(hi));
            }
        }
    }
    __syncthreads();   // all frags in regs before hs overwrites xs

#pragma unroll
    for (int ct = 0; ct < 20; ct++) {
        f32x4 acc = (f32x4){0.f, 0.f, 0.f, 0.f};
#pragma unroll
        for (int kc = 0; kc < 8; kc++) {
            const size_t fo = (size_t)((ct * 8 + kc) * 64 + l) * 8;
            bf16x8 wh = *(const bf16x8*)(whi + fo);
            bf16x8 wl = *(const bf16x8*)(wlo + fo);
            if (ct < 4) {   // D[wcol][xrow]
                acc = MFMA16(wh, xh[kc], acc, 0, 0, 0);
                acc = MFMA16(wh, xl[kc], acc, 0, 0, 0);
                acc = MFMA16(wl, xh[kc], acc, 0, 0, 0);
            } else {        // D[xrow][wcol]
                acc = MFMA16(xh[kc], wh, acc, 0, 0, 0);
                acc = MFMA16(xl[kc], wh, acc, 0, 0, 0);
                acc = MFMA16(xh[kc], wl, acc, 0, 0, 0);
            }
        }
        if (ct < 4) {
            const float* bias = (ct < 2) ? bfp : bgp;
            const int colbase = (ct & 1) * 16 + g * 4;
            float4 bv = *(const float4*)&bias[colbase];
            float v0 = acc[0] + bv.x, v1 = acc[1] + bv.y;
            float v2 = acc[2] + bv.z, v3 = acc[3] + bv.w;
            ushort h0 = bf16_rne(v0), h1 = bf16_rne(v1), h2 = bf16_rne(v2), h3 = bf16_rne(v3);
            ushort l0 = bf16_rne(v0 - bf16_to_f(h0)), l1 = bf16_rne(v1 - bf16_to_f(h1));
            ushort l2 = bf16_rne(v2 - bf16_to_f(h2)), l3 = bf16_rne(v3 - bf16_to_f(h3));
            uint2 hw, lw;
            hw.x = (unsigned)h0 | ((unsigned)h1 << 16); hw.y = (unsigned)h2 | ((unsigned)h3 << 16);
            lw.x = (unsigned)l0 | ((unsigned)l1 << 16); lw.y = (unsigned)l2 | ((unsigned)l3 << 16);
            const size_t o = (size_t)(rowbase + wv * 16 + a) * 32 + colbase;
            if (ct < 2) { *(uint2*)&fh[o] = hw; *(uint2*)&fl[o] = lw; }
            else        { *(uint2*)&gh[o] = hw; *(uint2*)&gl[o] = lw; }
        } else {
            // h rows n_loc = wv*16+g*4+r, col c -> hs[c][n_loc] (pad 80)
            const int c = (ct - 4) * 16 + a;
            const float bias = bhp[c];
            ushort h0 = bf16_rne(acc[0] + bias), h1 = bf16_rne(acc[1] + bias);
            ushort h2 = bf16_rne(acc[2] + bias), h3 = bf16_rne(acc[3] + bias);
            uint2 w;
            w.x = (unsigned)h0 | ((unsigned)h1 << 16);
            w.y = (unsigned)h2 | ((unsigned)h3 << 16);
            *(uint2*)&hs[c * 80 + wv * 16 + g * 4] = w;
        }
    }
    __syncthreads();   // h^T tile complete in LDS

    // coalesced h^T store: 8 passes x (256 thr x 16B)
#pragma unroll
    for (int p = 0; p < 8; p++) {
        const int c = p * 32 + (tid >> 3);
        const int col = (tid & 7) * 8;
        u32x4 v = *(const u32x4*)&hs[c * 80 + col];
        *(u32x4*)&ht[(size_t)(bb * 256 + c) * 4096 + n0 + col] = v;
    }
}

// ---------------- Kernel 2: MFMA flash attention, 2-phase pipelined ----------
// 512 blocks = (batch, 64-q tile); double-buffered LDS, ONE barrier per kt.
__global__ __launch_bounds__(256, 2) void attn_kernel(
    const ushort* __restrict__ fh, const ushort* __restrict__ fl,
    const ushort* __restrict__ gh, const ushort* __restrict__ gl,
    const ushort* __restrict__ ht, const float* __restrict__ x,
    const float* __restrict__ gammap, float* __restrict__ out)
{
    __shared__ __align__(16) ushort Fh[2][2048];
    __shared__ __align__(16) ushort Fl[2][2048];
    __shared__ __align__(16) ushort Hts[2][16384];

    const int tid = threadIdx.x;
    const int l = tid & 63, wv = tid >> 6;
    const int g = l >> 4, a = l & 15;
    const int bid = blockIdx.x;
    const int swzb = ((bid & 7) << 6) + (bid >> 3);   // bijective XCD swizzle
    const int b = swzb >> 6;
    const int q0 = (swzb & 63) * 64;
    const int base = b * NN;

    const size_t grow = (size_t)(base + q0 + wv * 16 + a) * CK_ + g * 8;
    const bf16x8 agh = *(const bf16x8*)(gh + grow);
    const bf16x8 agl = *(const bf16x8*)(gl + grow);

    float m = -1e30f, lsum = 0.f;   // per-lane softmax state (q = a)
    f32x4 acc[16];
#pragma unroll
    for (int ct = 0; ct < 16; ct++) acc[ct] = (f32x4){0.f, 0.f, 0.f, 0.f};

    auto stage = [&](int buf, int kt) {
        const size_t frow = (size_t)(base + kt * 64 + wv * 16 + a) * CK_ + g * 8;
        gload16(fh + frow, &Fh[buf][wv * 512]);
        gload16(fl + frow, &Fl[buf][wv * 512]);
#pragma unroll
        for (int i = 0; i < 8; i++) {
            const int fr = wv * 8 + i;
            const int khh = fr >> 4, ct = fr & 15;
            const ushort* hsrc = ht + (size_t)(b * 256 + ct * 16 + a) * 4096
                                    + (size_t)(kt * 64 + khh * 32 + g * 8);
            gload16(hsrc, &Hts[buf][fr * 512]);
        }
    };

    stage(0, 0);
    __syncthreads();   // drains vmcnt(0): buf0 ready

    for (int kt = 0; kt < NN / 64; kt++) {
        const int cur = kt & 1;
        if (kt < NN / 64 - 1) stage(cur ^ 1, kt + 1);   // issue early, lands under compute

        // ---- swapped QK^T: D[key][q]; lane: q = a, keys = s*16 + g*4 + r
        f32x4 s4[4];
#pragma unroll
        for (int s = 0; s < 4; s++) {
            bf16x8 bhk = *(const bf16x8*)&Fh[cur][(s * 64 + l) * 8];
            bf16x8 blk = *(const bf16x8*)&Fl[cur][(s * 64 + l) * 8];
            f32x4 z = (f32x4){0.f, 0.f, 0.f, 0.f};
            z = MFMA16(bhk, agh, z, 0, 0, 0);
            z = MFMA16(blk, agh, z, 0, 0, 0);
            z = MFMA16(bhk, agl, z, 0, 0, 0);
            s4[s] = z;
        }

        // ---- per-lane online softmax (16 keys/lane), reduce over g-groups
        float pm = s4[0][0];
#pragma unroll
        for (int s = 0; s < 4; s++)
#pragma unroll
            for (int r = 0; r < 4; r++) pm = fmaxf(pm, s4[s][r]);
        pm = fmaxf(pm, __shfl_xor(pm, 16));
        pm = fmaxf(pm, __shfl_xor(pm, 32));

        const int defer = (pm <= m + 8.f);
        if (!__all(defer)) {
            const float mn = fmaxf(m, pm);
            const float scq = __expf(m - mn);
            m = mn; lsum *= scq;
            float scr[4];
#pragma unroll
            for (int r = 0; r < 4; r++) scr[r] = __shfl(scq, g * 4 + r);
#pragma unroll
            for (int ct = 0; ct < 16; ct++)
#pragma unroll
                for (int r = 0; r < 4; r++) acc[ct][r] *= scr[r];
        }

        float p[4][4], rsum = 0.f;
#pragma unroll
        for (int s = 0; s < 4; s++)
#pragma unroll
            for (int r = 0; r < 4; r++) {
                const float pe = __expf(s4[s][r] - m);
                p[s][r] = pe;
                rsum += pe;
            }
        rsum += __shfl_xor(rsum, 16);
        rsum += __shfl_xor(rsum, 32);
        lsum += rsum;

        unsigned cw[4][2];
#pragma unroll
        for (int s = 0; s < 4; s++) {
            cw[s][0] = (unsigned)bf16_rne(p[s][0]) | ((unsigned)bf16_rne(p[s][1]) << 16);
            cw[s][1] = (unsigned)bf16_rne(p[s][2]) | ((unsigned)bf16_rne(p[s][3]) << 16);
        }

        // ---- PV: pa.word[w] = cw[kh*2+(g>>1)][w&1] from lane (2(g&1)+(w>>1))*16+a
        const int src0 = ((g & 1) << 5) + a;
        const int src1 = src0 + 16;
#pragma unroll
        for (int kh = 0; kh < 2; kh++) {
            const unsigned A0 = (unsigned)__shfl((int)cw[kh * 2][0], src0);
            const unsigned A1 = (unsigned)__shfl((int)cw[kh * 2][1], src0);
            const unsigned A2 = (unsigned)__shfl((int)cw[kh * 2][0], src1);
            const unsigned A3 = (unsigned)__shfl((int)cw[kh * 2][1], src1);
            const unsigned B0 = (unsigned)__shfl((int)cw[kh * 2 + 1][0], src0);
            const unsigned B1 = (unsigned)__shfl((int)cw[kh * 2 + 1][1], src0);
            const unsigned B2 = (unsigned)__shfl((int)cw[kh * 2 + 1][0], src1);
            const unsigned B3 = (unsigned)__shfl((int)cw[kh * 2 + 1][1], src1);
            const int hi = g >> 1;
            u32x4 pw;
            pw[0] = hi ? B0 : A0; pw[1] = hi ? B1 : A1;
            pw[2] = hi ? B2 : A2; pw[3] = hi ? B3 : A3;
            const bf16x8 pa = __builtin_bit_cast(bf16x8, pw);
#pragma unroll
            for (int ct = 0; ct < 16; ct++) {
                bf16x8 hb = *(const bf16x8*)&Hts[cur][((kh * 16 + ct) * 64 + l) * 8];
                acc[ct] = MFMA16(pa, hb, acc[ct], 0, 0, 0);
            }
        }

        __syncthreads();   // vmcnt(0)+lgkmcnt(0)+barrier: next buf ready, cur reusable
    }

    // ---- epilogue: out = gamma * acc/l + x ; acc rows q = g*4+r
    const float gamma = *gammap;
    const float inv = 1.f / lsum;
    float invr[4];
#pragma unroll
    for (int r = 0; r < 4; r++) invr[r] = __shfl(inv, g * 4 + r);
#pragma unroll
    for (int ct = 0; ct < 16; ct++) {
#pragma unroll
        for (int r = 0; r < 4; r++) {
            const int row = base + q0 + wv * 16 + g * 4 + r;
            const int o = row * C_ + ct * 16 + a;
            out[o] = fmaf(gamma, acc[ct][r] * invr[r], x[o]);
        }
    }
}

extern "C" void kernel_launch(void* const* d_in, const int* in_sizes, int n_in,
                              void* d_out, int out_size, void* d_ws, size_t ws_size,
                              hipStream_t stream) {
    const float* x     = (const float*)d_in[0];
    const float* Wf    = (const float*)d_in[1];
    const float* bfp   = (const float*)d_in[2];
    const float* Wg    = (const float*)d_in[3];
    const float* bgp   = (const float*)d_in[4];
    const float* Wh    = (const float*)d_in[5];
    const float* bhp   = (const float*)d_in[6];
    const float* gamma = (const float*)d_in[7];
    float* out = (float*)d_out;

    const size_t npix = (size_t)B_ * NN;
    ushort* fh  = (ushort*)d_ws;             // [B*N][32] bf16 hi
    ushort* fl  = fh + npix * CK_;
    ushort* gh  = fl + npix * CK_;
    ushort* gl  = gh + npix * CK_;
    ushort* ht  = gl + npix * CK_;           // [B][256][4096] bf16 (h^T)
    ushort* whi = ht + (size_t)B_ * C_ * NN; // W fragments
    ushort* wlo = whi + 20 * 8 * 64 * 8;

    prep_kernel<<<320, 256, 0, stream>>>(Wf, Wg, Wh, whi, wlo);
    proj_kernel<<<(B_ * NN) / 64, 256, 0, stream>>>(x, whi, wlo, bfp, bgp, bhp,
                                                    fh, fl, gh, gl, ht);
    attn_kernel<<<B_ * (NN / 64), 256, 0, stream>>>(fh, fl, gh, gl, ht, x, gamma, out);
}